// Round 2
// baseline (133.936 us; speedup 1.0000x reference)
//
#include <hip/hip_runtime.h>
#include <stdint.h>

#define NN 6144
#define NUSER 4096
#define RR 2
#define KK 3
#define FIN 25
#define FOUT 64
#define DD2 64
#define CAP 320

__device__ __forceinline__ float wave_reduce_sum(float v) {
    #pragma unroll
    for (int off = 32; off >= 1; off >>= 1) v += __shfl_xor(v, off);
    return v;
}
__device__ __forceinline__ float wave_reduce_max(float v) {
    #pragma unroll
    for (int off = 32; off >= 1; off >>= 1) v = fmaxf(v, __shfl_xor(v, off));
    return v;
}

// Probe hadj encoding: int32 {0,1} vs 1-byte bool. Diagonal (self-loops) must
// be all-1 under int32 reads at stride NN+1; under byte encoding those reads
// hit pseudo-random packed bytes and essentially cannot all equal exactly 1.
__global__ __launch_bounds__(64) void k0_detect(const int* __restrict__ hadj32,
                                                int* __restrict__ flag)
{
    const int lane = threadIdx.x;
    const int v = hadj32[(size_t)lane * (NN + 1)];
    const unsigned long long ok = __ballot(v == 1);
    if (lane == 0) *flag = (ok == ~0ull) ? 1 : 0;
}

// One wave per (r,k,n): hp[rk,n,:] = h[n,:] @ w[rk,:,:]; s,d scalars.
__global__ __launch_bounds__(64) void k1_proj(
    const float* __restrict__ h, const float* __restrict__ w,
    const float* __restrict__ asrc, const float* __restrict__ adst,
    float* __restrict__ hp, float* __restrict__ s, float* __restrict__ d)
{
    const int row = blockIdx.x;          // rk*NN + n
    const int rk = row / NN;
    const int n  = row % NN;
    const int o  = threadIdx.x;

    const float* hrow = h + (size_t)n * FIN;
    const float* wp   = w + (size_t)rk * FIN * FOUT + o;
    float acc = 0.f;
    #pragma unroll
    for (int f = 0; f < FIN; ++f) acc += hrow[f] * wp[f * FOUT];

    hp[((size_t)rk * NN + n) * FOUT + o] = acc;
    float sv = wave_reduce_sum(acc * asrc[rk * FOUT + o]);
    float dv = wave_reduce_sum(acc * adst[rk * FOUT + o]);
    if (o == 0) {
        s[rk * NN + n] = sv;
        d[rk * NN + n] = dv;
    }
}

// One wave per (r,n): scan adjacency row -> neighbor list (LDS),
// per-head neighbor softmax + gather-accumulate hp, mean over heads + bias.
__global__ __launch_bounds__(64) void k2_gat(
    const void* __restrict__ hadj_raw, const int* __restrict__ flag,
    const float* __restrict__ hp, const float* __restrict__ s,
    const float* __restrict__ d, const float* __restrict__ bias,
    float* __restrict__ embs)
{
    const int row  = blockIdx.x;         // r*NN + n
    const int r    = row / NN;
    const int n    = row % NN;
    const int lane = threadIdx.x;
    const int enc32 = *flag;             // uniform across grid

    __shared__ int   nbr[CAP];
    __shared__ float pw[CAP];

    int base = 0;
    if (enc32) {
        // ---- int32 {0,1} encoding: 6144 ints = 24 iters x (64 lanes x int4)
        const int* rowp = (const int*)hadj_raw + (size_t)row * NN;
        for (int t = 0; t < 24; ++t) {
            const int m0 = t * 256 + lane * 4;
            const int4 v = *reinterpret_cast<const int4*>(rowp + m0);
            const int vv[4] = {v.x, v.y, v.z, v.w};
            int c = (v.x != 0) + (v.y != 0) + (v.z != 0) + (v.w != 0);
            int pre = c;
            #pragma unroll
            for (int off = 1; off < 64; off <<= 1) {
                int up = __shfl_up(pre, off);
                if (lane >= off) pre += up;
            }
            int myoff = base + pre - c;
            const int total = __shfl(pre, 63);
            #pragma unroll
            for (int q = 0; q < 4; ++q) {
                if (vv[q] != 0) {
                    if (myoff < CAP) nbr[myoff] = m0 + q;
                    myoff++;
                }
            }
            base += total;
        }
    } else {
        // ---- 1-byte encoding: 6144 B = 6 iters x (64 lanes x 16 B)
        const uint8_t* rowp = (const uint8_t*)hadj_raw + (size_t)row * NN;
        #pragma unroll
        for (int t = 0; t < 6; ++t) {
            const int m0 = t * 1024 + lane * 16;
            const uint4 v = *reinterpret_cast<const uint4*>(rowp + m0);
            const unsigned int wd[4] = {v.x, v.y, v.z, v.w};
            int c = 0;
            #pragma unroll
            for (int q = 0; q < 4; ++q) {
                unsigned int x = wd[q];
                c += (x & 0x000000ffu) ? 1 : 0;
                c += (x & 0x0000ff00u) ? 1 : 0;
                c += (x & 0x00ff0000u) ? 1 : 0;
                c += (x & 0xff000000u) ? 1 : 0;
            }
            int pre = c;
            #pragma unroll
            for (int off = 1; off < 64; off <<= 1) {
                int up = __shfl_up(pre, off);
                if (lane >= off) pre += up;
            }
            int myoff = base + pre - c;
            const int total = __shfl(pre, 63);
            #pragma unroll
            for (int q = 0; q < 4; ++q) {
                unsigned int x = wd[q];
                #pragma unroll
                for (int b = 0; b < 4; ++b) {
                    if ((x >> (8 * b)) & 0xffu) {
                        if (myoff < CAP) nbr[myoff] = m0 + q * 4 + b;
                        myoff++;
                    }
                }
            }
            base += total;
        }
    }
    const int count = base > CAP ? CAP : base;
    __syncthreads();

    // ---- per-head masked softmax + PV gather
    float tot = 0.f;
    #pragma unroll
    for (int k = 0; k < KK; ++k) {
        const float* dk = d + (size_t)(r * KK + k) * NN;
        const float  sk = s[(size_t)(r * KK + k) * NN + n];

        float mx = -1e30f;
        for (int j = lane; j < count; j += 64) {
            float e = sk + dk[nbr[j]];
            e = (e >= 0.f) ? e : 0.2f * e;   // leaky_relu 0.2
            pw[j] = e;
            mx = fmaxf(mx, e);
        }
        mx = wave_reduce_max(mx);

        float ssum = 0.f;
        for (int j = lane; j < count; j += 64) {
            float p = __expf(pw[j] - mx);
            pw[j] = p;
            ssum += p;
        }
        ssum = wave_reduce_sum(ssum);
        __syncthreads();   // pw visible to all lanes

        const float* hpk = hp + ((size_t)(r * KK + k) * NN) * FOUT + lane;
        float acc = 0.f;
        for (int j = 0; j < count; ++j) {
            acc += pw[j] * hpk[(size_t)nbr[j] * FOUT];
        }
        tot += acc / ssum;
        __syncthreads();   // before pw is overwritten next head
    }

    embs[(size_t)row * FOUT + lane] = tot * (1.f / 3.f) + bias[r * FOUT + lane];
}

// One wave per user node: semantic attention fusion + classifier + log_softmax.
__global__ __launch_bounds__(64) void k3_fuse(
    const float* __restrict__ h, const float* __restrict__ embs,
    const float* __restrict__ aw1, const float* __restrict__ aw2,
    const float* __restrict__ am, const float* __restrict__ fcw,
    const float* __restrict__ fcb, float* __restrict__ out)
{
    const int n = blockIdx.x;
    const int o = threadIdx.x;

    __shared__ float sh[2][FOUT];
    const float ta0 = embs[((size_t)0 * NN + n) * FOUT + o];
    const float ta1 = embs[((size_t)1 * NN + n) * FOUT + o];
    sh[0][o] = ta0;
    sh[1][o] = ta1;

    float fa = 0.f;
    const float* hrow = h + (size_t)n * FIN;
    #pragma unroll
    for (int f = 0; f < FIN; ++f) fa += hrow[f] * aw1[f * DD2 + o];
    __syncthreads();

    float e[2];
    #pragma unroll
    for (int r = 0; r < 2; ++r) {
        float t = fa;
        #pragma unroll 8
        for (int j = 0; j < FOUT; ++j) t += sh[r][j] * aw2[j * DD2 + o];
        float q = tanhf(t);
        e[r] = wave_reduce_sum(q * am[o]);
    }
    const float mx = fmaxf(e[0], e[1]);
    float b0 = __expf(e[0] - mx), b1 = __expf(e[1] - mx);
    const float inv = 1.f / (b0 + b1);
    b0 *= inv; b1 *= inv;
    const float fus = b0 * ta0 + b1 * ta1;

    // cat = [ta0 (64), ta1 (64), fusion (64)] @ fc_w(192,2)
    float p0 = ta0 * fcw[(o      ) * 2 + 0] + ta1 * fcw[(64 + o) * 2 + 0] + fus * fcw[(128 + o) * 2 + 0];
    float p1 = ta0 * fcw[(o      ) * 2 + 1] + ta1 * fcw[(64 + o) * 2 + 1] + fus * fcw[(128 + o) * 2 + 1];
    const float lg0 = wave_reduce_sum(p0) + fcb[0];
    const float lg1 = wave_reduce_sum(p1) + fcb[1];

    if (o == 0) {
        const float m2  = fmaxf(lg0, lg1);
        const float lse = m2 + logf(__expf(lg0 - m2) + __expf(lg1 - m2));
        out[(size_t)n * 2 + 0] = lg0 - lse;
        out[(size_t)n * 2 + 1] = lg1 - lse;
    }
}

extern "C" void kernel_launch(void* const* d_in, const int* in_sizes, int n_in,
                              void* d_out, int out_size, void* d_ws, size_t ws_size,
                              hipStream_t stream)
{
    const void*  hadj = d_in[0];
    const float* h    = (const float*)d_in[1];
    const float* w    = (const float*)d_in[2];
    const float* asrc = (const float*)d_in[3];
    const float* adst = (const float*)d_in[4];
    const float* bias = (const float*)d_in[5];
    const float* aw1  = (const float*)d_in[6];
    const float* aw2  = (const float*)d_in[7];
    const float* am   = (const float*)d_in[8];
    const float* fcw  = (const float*)d_in[9];
    const float* fcb  = (const float*)d_in[10];
    float* out = (float*)d_out;

    int*   flag = (int*)d_ws;                          // 64 B reserved
    float* ws   = (float*)d_ws + 16;
    float* hp   = ws;                                  // RR*KK*NN*FOUT
    float* s    = hp + (size_t)RR * KK * NN * FOUT;    // RR*KK*NN
    float* d    = s  + (size_t)RR * KK * NN;           // RR*KK*NN
    float* embs = d  + (size_t)RR * KK * NN;           // RR*NN*FOUT

    k0_detect<<<1, 64, 0, stream>>>((const int*)hadj, flag);
    k1_proj<<<RR * KK * NN, 64, 0, stream>>>(h, w, asrc, adst, hp, s, d);
    k2_gat <<<RR * NN,      64, 0, stream>>>(hadj, flag, hp, s, d, bias, embs);
    k3_fuse<<<NUSER,        64, 0, stream>>>(h, embs, aw1, aw2, am, fcw, fcb, out);
}

// Round 3
// 118.691 us; speedup vs baseline: 1.1284x; 1.1284x over previous
//
#include <hip/hip_runtime.h>
#include <stdint.h>

#define NN 6144
#define NUSER 4096
#define RR 2
#define KK 3
#define FIN 25
#define FOUT 64
#define DD2 64
#define CAP 192

__device__ __forceinline__ float wave_reduce_sum(float v) {
    #pragma unroll
    for (int off = 32; off >= 1; off >>= 1) v += __shfl_xor(v, off);
    return v;
}
__device__ __forceinline__ float wave_reduce_max(float v) {
    #pragma unroll
    for (int off = 32; off >= 1; off >>= 1) v = fmaxf(v, __shfl_xor(v, off));
    return v;
}
__device__ __forceinline__ unsigned short f2bf(float x) {   // RNE
    unsigned int u = __float_as_uint(x);
    unsigned int r = (u + 0x7fffu + ((u >> 16) & 1u)) >> 16;
    return (unsigned short)r;
}
__device__ __forceinline__ float bf2f(unsigned short b) {
    return __uint_as_float(((unsigned int)b) << 16);
}

// One wave per (r,n): hp for all 3 heads (packed bf16 ushort4) + s,d float4.
__global__ __launch_bounds__(128) void k1_proj(
    const float* __restrict__ h, const float* __restrict__ w,
    const float* __restrict__ asrc, const float* __restrict__ adst,
    ushort4* __restrict__ hpq, float4* __restrict__ sq, float4* __restrict__ dq)
{
    const int wid  = threadIdx.x >> 6;
    const int lane = threadIdx.x & 63;
    const int row  = blockIdx.x * 2 + wid;     // r*NN + n
    const int r    = row / NN;
    const int n    = row % NN;

    const float* hrow = h + (size_t)n * FIN;
    float acc[KK];
    #pragma unroll
    for (int k = 0; k < KK; ++k) {
        const float* wp = w + ((size_t)(r * KK + k) * FIN) * FOUT + lane;
        float a = 0.f;
        #pragma unroll
        for (int f = 0; f < FIN; ++f) a += hrow[f] * wp[f * FOUT];
        acc[k] = a;
    }

    ushort4 pk;
    pk.x = f2bf(acc[0]); pk.y = f2bf(acc[1]); pk.z = f2bf(acc[2]); pk.w = 0;
    hpq[(size_t)row * FOUT + lane] = pk;

    float sv0 = wave_reduce_sum(acc[0] * asrc[(r * KK + 0) * FOUT + lane]);
    float sv1 = wave_reduce_sum(acc[1] * asrc[(r * KK + 1) * FOUT + lane]);
    float sv2 = wave_reduce_sum(acc[2] * asrc[(r * KK + 2) * FOUT + lane]);
    float dv0 = wave_reduce_sum(acc[0] * adst[(r * KK + 0) * FOUT + lane]);
    float dv1 = wave_reduce_sum(acc[1] * adst[(r * KK + 1) * FOUT + lane]);
    float dv2 = wave_reduce_sum(acc[2] * adst[(r * KK + 2) * FOUT + lane]);
    if (lane == 0) {
        sq[row] = make_float4(sv0, sv1, sv2, 0.f);
        dq[row] = make_float4(dv0, dv1, dv2, 0.f);
    }
}

// One wave per (r,n): int32 adjacency scan -> neighbor list, fused 3-head
// softmax, single packed-bf16 PV gather.
__global__ __launch_bounds__(128) void k2_gat(
    const int* __restrict__ hadj, const ushort4* __restrict__ hpq,
    const float4* __restrict__ sq, const float4* __restrict__ dq,
    const float* __restrict__ bias, float* __restrict__ embs)
{
    const int wid  = threadIdx.x >> 6;
    const int lane = threadIdx.x & 63;
    const int row  = blockIdx.x * 2 + wid;     // r*NN + n
    const int r    = row / NN;

    __shared__ int   nbr_s[2][CAP];
    __shared__ float pw_s[2][3][CAP];
    int* nbr = nbr_s[wid];
    float (*pw)[CAP] = pw_s[wid];

    // ---- scan: 6144 int32 = 24 iters x (64 lanes x int4)
    const int* rowp = hadj + (size_t)row * NN;
    int base = 0;
    for (int t = 0; t < 24; ++t) {
        const int m0 = t * 256 + lane * 4;
        const int4 v = *reinterpret_cast<const int4*>(rowp + m0);
        const int vv[4] = {v.x, v.y, v.z, v.w};
        int c = (v.x != 0) + (v.y != 0) + (v.z != 0) + (v.w != 0);
        int pre = c;
        #pragma unroll
        for (int off = 1; off < 64; off <<= 1) {
            int up = __shfl_up(pre, off);
            if (lane >= off) pre += up;
        }
        int myoff = base + pre - c;
        const int total = __shfl(pre, 63);
        #pragma unroll
        for (int q = 0; q < 4; ++q) {
            if (vv[q] != 0) {
                if (myoff < CAP) nbr[myoff] = m0 + q;
                myoff++;
            }
        }
        base += total;
    }
    const int count = base > CAP ? CAP : base;
    __syncthreads();

    // ---- fused 3-head attention logits (one float4 d-gather per neighbor)
    const float4 sv = sq[row];
    const float4* dqr = dq + (size_t)r * NN;
    float mx0 = -1e30f, mx1 = -1e30f, mx2 = -1e30f;
    for (int j = lane; j < count; j += 64) {
        const float4 dv = dqr[nbr[j]];
        float e0 = sv.x + dv.x; e0 = (e0 >= 0.f) ? e0 : 0.2f * e0;
        float e1 = sv.y + dv.y; e1 = (e1 >= 0.f) ? e1 : 0.2f * e1;
        float e2 = sv.z + dv.z; e2 = (e2 >= 0.f) ? e2 : 0.2f * e2;
        pw[0][j] = e0; pw[1][j] = e1; pw[2][j] = e2;
        mx0 = fmaxf(mx0, e0); mx1 = fmaxf(mx1, e1); mx2 = fmaxf(mx2, e2);
    }
    mx0 = wave_reduce_max(mx0);
    mx1 = wave_reduce_max(mx1);
    mx2 = wave_reduce_max(mx2);

    float ss0 = 0.f, ss1 = 0.f, ss2 = 0.f;
    for (int j = lane; j < count; j += 64) {   // same j-set each lane wrote
        float p0 = __expf(pw[0][j] - mx0); pw[0][j] = p0; ss0 += p0;
        float p1 = __expf(pw[1][j] - mx1); pw[1][j] = p1; ss1 += p1;
        float p2 = __expf(pw[2][j] - mx2); pw[2][j] = p2; ss2 += p2;
    }
    ss0 = wave_reduce_sum(ss0);
    ss1 = wave_reduce_sum(ss1);
    ss2 = wave_reduce_sum(ss2);
    __syncthreads();

    // ---- PV gather: one ushort4 (3 heads bf16) load per neighbor per lane
    const ushort4* hq = hpq + ((size_t)r * NN) * FOUT + lane;
    float a0 = 0.f, a1 = 0.f, a2 = 0.f;
    int j = 0;
    for (; j + 4 <= count; j += 4) {
        #pragma unroll
        for (int u = 0; u < 4; ++u) {
            const ushort4 v = hq[(size_t)nbr[j + u] * FOUT];
            a0 += pw[0][j + u] * bf2f(v.x);
            a1 += pw[1][j + u] * bf2f(v.y);
            a2 += pw[2][j + u] * bf2f(v.z);
        }
    }
    for (; j < count; ++j) {
        const ushort4 v = hq[(size_t)nbr[j] * FOUT];
        a0 += pw[0][j] * bf2f(v.x);
        a1 += pw[1][j] * bf2f(v.y);
        a2 += pw[2][j] * bf2f(v.z);
    }

    const float tot = a0 / ss0 + a1 / ss1 + a2 / ss2;
    embs[(size_t)row * FOUT + lane] = tot * (1.f / 3.f) + bias[r * FOUT + lane];
}

// One wave per user node: semantic attention fusion + classifier + log_softmax.
__global__ __launch_bounds__(64) void k3_fuse(
    const float* __restrict__ h, const float* __restrict__ embs,
    const float* __restrict__ aw1, const float* __restrict__ aw2,
    const float* __restrict__ am, const float* __restrict__ fcw,
    const float* __restrict__ fcb, float* __restrict__ out)
{
    const int n = blockIdx.x;
    const int o = threadIdx.x;

    __shared__ float sh[2][FOUT];
    const float ta0 = embs[((size_t)0 * NN + n) * FOUT + o];
    const float ta1 = embs[((size_t)1 * NN + n) * FOUT + o];
    sh[0][o] = ta0;
    sh[1][o] = ta1;

    float fa = 0.f;
    const float* hrow = h + (size_t)n * FIN;
    #pragma unroll
    for (int f = 0; f < FIN; ++f) fa += hrow[f] * aw1[f * DD2 + o];
    __syncthreads();

    float e[2];
    #pragma unroll
    for (int r = 0; r < 2; ++r) {
        float t = fa;
        #pragma unroll 8
        for (int j = 0; j < FOUT; ++j) t += sh[r][j] * aw2[j * DD2 + o];
        float q = tanhf(t);
        e[r] = wave_reduce_sum(q * am[o]);
    }
    const float mx = fmaxf(e[0], e[1]);
    float b0 = __expf(e[0] - mx), b1 = __expf(e[1] - mx);
    const float inv = 1.f / (b0 + b1);
    b0 *= inv; b1 *= inv;
    const float fus = b0 * ta0 + b1 * ta1;

    float p0 = ta0 * fcw[(o      ) * 2 + 0] + ta1 * fcw[(64 + o) * 2 + 0] + fus * fcw[(128 + o) * 2 + 0];
    float p1 = ta0 * fcw[(o      ) * 2 + 1] + ta1 * fcw[(64 + o) * 2 + 1] + fus * fcw[(128 + o) * 2 + 1];
    const float lg0 = wave_reduce_sum(p0) + fcb[0];
    const float lg1 = wave_reduce_sum(p1) + fcb[1];

    if (o == 0) {
        const float m2  = fmaxf(lg0, lg1);
        const float lse = m2 + logf(__expf(lg0 - m2) + __expf(lg1 - m2));
        out[(size_t)n * 2 + 0] = lg0 - lse;
        out[(size_t)n * 2 + 1] = lg1 - lse;
    }
}

extern "C" void kernel_launch(void* const* d_in, const int* in_sizes, int n_in,
                              void* d_out, int out_size, void* d_ws, size_t ws_size,
                              hipStream_t stream)
{
    const int*   hadj = (const int*)d_in[0];
    const float* h    = (const float*)d_in[1];
    const float* w    = (const float*)d_in[2];
    const float* asrc = (const float*)d_in[3];
    const float* adst = (const float*)d_in[4];
    const float* bias = (const float*)d_in[5];
    const float* aw1  = (const float*)d_in[6];
    const float* aw2  = (const float*)d_in[7];
    const float* am   = (const float*)d_in[8];
    const float* fcw  = (const float*)d_in[9];
    const float* fcb  = (const float*)d_in[10];
    float* out = (float*)d_out;

    char* ws = (char*)d_ws;
    ushort4* hpq = (ushort4*)ws;                       // RR*NN*64*8 B = 6.29 MB
    ws += (size_t)RR * NN * FOUT * sizeof(ushort4);
    float4* sq = (float4*)ws;                          // RR*NN*16 B
    ws += (size_t)RR * NN * sizeof(float4);
    float4* dq = (float4*)ws;                          // RR*NN*16 B
    ws += (size_t)RR * NN * sizeof(float4);
    float* embs = (float*)ws;                          // RR*NN*64*4 B

    k1_proj<<<RR * NN / 2, 128, 0, stream>>>(h, w, asrc, adst, hpq, sq, dq);
    k2_gat <<<RR * NN / 2, 128, 0, stream>>>(hadj, hpq, sq, dq, bias, embs);
    k3_fuse<<<NUSER, 64, 0, stream>>>(h, embs, aw1, aw2, am, fcw, fcb, out);
}